// Round 1
// baseline (909.242 us; speedup 1.0000x reference)
//
#include <hip/hip_runtime.h>

#define DD 64
#define FIN 128

__global__ __launch_bounds__(256) void k_deg_init(int* __restrict__ deg, int n) {
    int i = blockIdx.x * 256 + threadIdx.x;
    if (i < n) deg[i] = 1;  // self-loop
}

__global__ __launch_bounds__(256) void k_deg_count(const int* __restrict__ dst,
                                                   int* __restrict__ deg, int E) {
    int e = blockIdx.x * 256 + threadIdx.x;
    if (e < E) atomicAdd(&deg[dst[e]], 1);
}

__global__ __launch_bounds__(256) void k_rs(const int* __restrict__ deg,
                                            float* __restrict__ rs, int n) {
    int i = blockIdx.x * 256 + threadIdx.x;
    if (i < n) rs[i] = rsqrtf((float)deg[i]);
}

// out[n,64] = x[n,128] @ W[128,64]
__global__ __launch_bounds__(256) void k_gemm1(const float* __restrict__ x,
                                               const float* __restrict__ W,
                                               float* __restrict__ out, int n) {
    __shared__ float sW[FIN * DD];
    __shared__ float sx[4][FIN];
    for (int i = threadIdx.x; i < FIN * DD; i += 256) sW[i] = W[i];
    __syncthreads();
    int col = threadIdx.x & 63;
    int rq  = threadIdx.x >> 6;
    for (int base = blockIdx.x * 4; base < n; base += gridDim.x * 4) {
        int row = base + rq;
        if (row < n) {
            // each wave stages and consumes its own row: no cross-wave sync needed
            sx[rq][col]      = x[(size_t)row * FIN + col];
            sx[rq][col + 64] = x[(size_t)row * FIN + col + 64];
            float acc = 0.f;
#pragma unroll
            for (int k = 0; k < FIN; ++k) acc = fmaf(sx[rq][k], sW[k * DD + col], acc);
            out[(size_t)row * DD + col] = acc;
        }
    }
}

// out[n,64] = relu(a[n,64]) @ W[64,64]
__global__ __launch_bounds__(256) void k_gemm2(const float* __restrict__ a,
                                               const float* __restrict__ W,
                                               float* __restrict__ out, int n) {
    __shared__ float sW[DD * DD];
    __shared__ float sx[4][DD];
    for (int i = threadIdx.x; i < DD * DD; i += 256) sW[i] = W[i];
    __syncthreads();
    int col = threadIdx.x & 63;
    int rq  = threadIdx.x >> 6;
    for (int base = blockIdx.x * 4; base < n; base += gridDim.x * 4) {
        int row = base + rq;
        if (row < n) {
            sx[rq][col] = fmaxf(a[(size_t)row * DD + col], 0.f);
            float acc = 0.f;
#pragma unroll
            for (int k = 0; k < DD; ++k) acc = fmaf(sx[rq][k], sW[k * DD + col], acc);
            out[(size_t)row * DD + col] = acc;
        }
    }
}

// agg[i][c] = b[c] + pert[i][c] + h[i][c] * rs[i]^2   (self-loop norm = 1/deg)
__global__ __launch_bounds__(256) void k_init(const float* __restrict__ h,
                                              const float* __restrict__ b,
                                              const float* __restrict__ pert,
                                              const float* __restrict__ rs,
                                              float* __restrict__ agg, int n) {
    size_t total = (size_t)n * DD;
    for (size_t idx = (size_t)blockIdx.x * 256 + threadIdx.x; idx < total;
         idx += (size_t)gridDim.x * 256) {
        int row = (int)(idx >> 6);
        int c   = (int)(idx & 63);
        float r = rs[row];
        agg[idx] = b[c] + pert[idx] + h[idx] * r * r;
    }
}

// one wave per edge: lane = feature column
__global__ __launch_bounds__(256) void k_scatter(const float* __restrict__ h,
                                                 const int* __restrict__ src,
                                                 const int* __restrict__ dst,
                                                 const float* __restrict__ rs,
                                                 float* __restrict__ agg, int E) {
    int lane = threadIdx.x & 63;
    int w    = threadIdx.x >> 6;
    for (long e = (long)blockIdx.x * 4 + w; e < E; e += (long)gridDim.x * 4) {
        int s = src[e], d = dst[e];
        float nrm = rs[s] * rs[d];
        float v = h[(size_t)s * DD + lane] * nrm;
        atomicAdd(&agg[(size_t)d * DD + lane], v);
    }
}

extern "C" void kernel_launch(void* const* d_in, const int* in_sizes, int n_in,
                              void* d_out, int out_size, void* d_ws, size_t ws_size,
                              hipStream_t stream) {
    const float* x  = (const float*)d_in[0];
    const int*   ei = (const int*)d_in[1];
    const float* W1 = (const float*)d_in[2];
    const float* b1 = (const float*)d_in[3];
    const float* W2 = (const float*)d_in[4];
    const float* b2 = (const float*)d_in[5];
    const float* p1 = (const float*)d_in[6];
    const float* p2 = (const float*)d_in[7];
    float* out = (float*)d_out;

    int n = in_sizes[0] / FIN;
    int E = in_sizes[1] / 2;
    const int* src = ei;
    const int* dst = ei + E;

    char* ws  = (char*)d_ws;
    int*   deg  = (int*)ws;
    float* rs   = (float*)(ws + sizeof(int) * (size_t)n);
    float* h1   = rs + n;
    float* agg1 = h1 + (size_t)n * DD;
    float* h2   = agg1 + (size_t)n * DD;

    int nb  = (n + 255) / 256;
    int eb  = (E + 255) / 256;
    int ewb = (E + 3) / 4;  // one wave per edge, 4 waves/block

    k_deg_init<<<nb, 256, 0, stream>>>(deg, n);
    k_deg_count<<<eb, 256, 0, stream>>>(dst, deg, E);
    k_rs<<<nb, 256, 0, stream>>>(deg, rs, n);

    k_gemm1<<<2048, 256, 0, stream>>>(x, W1, h1, n);
    k_init<<<4096, 256, 0, stream>>>(h1, b1, p1, rs, agg1, n);
    k_scatter<<<ewb, 256, 0, stream>>>(h1, src, dst, rs, agg1, E);

    k_gemm2<<<2048, 256, 0, stream>>>(agg1, W2, h2, n);
    k_init<<<4096, 256, 0, stream>>>(h2, b2, p2, rs, out, n);
    k_scatter<<<ewb, 256, 0, stream>>>(h2, src, dst, rs, out, E);
}

// Round 2
// 550.523 us; speedup vs baseline: 1.6516x; 1.6516x over previous
//
#include <hip/hip_runtime.h>

#define DD 64
#define FIN 128

__global__ __launch_bounds__(256) void k_deg_init(int* __restrict__ deg, int n) {
    int i = blockIdx.x * 256 + threadIdx.x;
    if (i < n) deg[i] = 1;  // self-loop
}

__global__ __launch_bounds__(256) void k_deg_count(const int* __restrict__ dst,
                                                   int* __restrict__ deg, int E) {
    int e = blockIdx.x * 256 + threadIdx.x;
    if (e < E) atomicAdd(&deg[dst[e]], 1);
}

__global__ __launch_bounds__(256) void k_rs(const int* __restrict__ deg,
                                            float* __restrict__ rs, int n) {
    int i = blockIdx.x * 256 + threadIdx.x;
    if (i < n) rs[i] = rsqrtf((float)deg[i]);
}

// exclusive scan of (deg[i]-1) -> rowptr[0..n], single workgroup of 1024
__global__ __launch_bounds__(1024) void k_scan(const int* __restrict__ deg,
                                               int* __restrict__ rowptr, int n) {
    __shared__ int ws_sums[16];
    __shared__ int s_carry;
    if (threadIdx.x == 0) s_carry = 0;
    __syncthreads();
    int lane = threadIdx.x & 63, wid = threadIdx.x >> 6;
    for (int base = 0; base < n; base += 1024) {
        int i = base + (int)threadIdx.x;
        int v = (i < n) ? (deg[i] - 1) : 0;  // raw edge count (minus self-loop)
        int s = v;
        for (int off = 1; off < 64; off <<= 1) {
            int t = __shfl_up(s, off, 64);
            if (lane >= off) s += t;
        }
        if (lane == 63) ws_sums[wid] = s;
        __syncthreads();
        int waveoff = 0;
        for (int w = 0; w < wid; ++w) waveoff += ws_sums[w];
        int incl = s + waveoff + s_carry;
        if (i < n) rowptr[i] = incl - v;  // exclusive
        __syncthreads();
        if (threadIdx.x == 1023) s_carry = incl;
        __syncthreads();
    }
    if (threadIdx.x == 0) rowptr[n] = s_carry;
}

// scatter edges into CSR slots; precompute per-edge norm
__global__ __launch_bounds__(256) void k_place(const int* __restrict__ src,
                                               const int* __restrict__ dst,
                                               const float* __restrict__ rs,
                                               const int* __restrict__ rowptr,
                                               int* __restrict__ cursor,
                                               int* __restrict__ es,
                                               float* __restrict__ enorm, int E) {
    int e = blockIdx.x * 256 + threadIdx.x;
    if (e < E) {
        int s = src[e], d = dst[e];
        int pos = rowptr[d] + atomicAdd(&cursor[d], 1);
        es[pos] = s;
        enorm[pos] = rs[s] * rs[d];
    }
}

// out[n,64] = x[n,128] @ W[128,64]
__global__ __launch_bounds__(256) void k_gemm1(const float* __restrict__ x,
                                               const float* __restrict__ W,
                                               float* __restrict__ out, int n) {
    __shared__ float sW[FIN * DD];
    __shared__ float sx[4][FIN];
    for (int i = threadIdx.x; i < FIN * DD; i += 256) sW[i] = W[i];
    __syncthreads();
    int col = threadIdx.x & 63;
    int rq  = threadIdx.x >> 6;
    for (int base = blockIdx.x * 4; base < n; base += gridDim.x * 4) {
        int row = base + rq;
        if (row < n) {
            sx[rq][col]      = x[(size_t)row * FIN + col];
            sx[rq][col + 64] = x[(size_t)row * FIN + col + 64];
            float acc = 0.f;
#pragma unroll
            for (int k = 0; k < FIN; ++k) acc = fmaf(sx[rq][k], sW[k * DD + col], acc);
            out[(size_t)row * DD + col] = acc;
        }
    }
}

// out[n,64] = relu(a[n,64]) @ W[64,64]
__global__ __launch_bounds__(256) void k_gemm2(const float* __restrict__ a,
                                               const float* __restrict__ W,
                                               float* __restrict__ out, int n) {
    __shared__ float sW[DD * DD];
    __shared__ float sx[4][DD];
    for (int i = threadIdx.x; i < DD * DD; i += 256) sW[i] = W[i];
    __syncthreads();
    int col = threadIdx.x & 63;
    int rq  = threadIdx.x >> 6;
    for (int base = blockIdx.x * 4; base < n; base += gridDim.x * 4) {
        int row = base + rq;
        if (row < n) {
            sx[rq][col] = fmaxf(a[(size_t)row * DD + col], 0.f);
            float acc = 0.f;
#pragma unroll
            for (int k = 0; k < DD; ++k) acc = fmaf(sx[rq][k], sW[k * DD + col], acc);
            out[(size_t)row * DD + col] = acc;
        }
    }
}

// gather-based aggregation: one wave per dst node, lane = column.
// out[i] = b + pert[i] + h[i]/deg[i] + sum_e h[src_e]*norm_e
__global__ __launch_bounds__(256) void k_agg(const float* __restrict__ h,
                                             const int* __restrict__ es,
                                             const float* __restrict__ enorm,
                                             const int* __restrict__ rowptr,
                                             const float* __restrict__ rs,
                                             const float* __restrict__ b,
                                             const float* __restrict__ pert,
                                             float* __restrict__ outp, int n) {
    int lane = threadIdx.x & 63;
    int w    = threadIdx.x >> 6;
    int node = blockIdx.x * 4 + w;
    if (node >= n) return;
    float r = rs[node];
    size_t rowoff = (size_t)node * DD + lane;
    float acc = b[lane] + pert[rowoff] + h[rowoff] * r * r;
    int e  = rowptr[node];
    int e1 = rowptr[node + 1];
    for (; e + 4 <= e1; e += 4) {
        int s0 = es[e], s1 = es[e + 1], s2 = es[e + 2], s3 = es[e + 3];
        float n0 = enorm[e], n1 = enorm[e + 1], n2 = enorm[e + 2], n3 = enorm[e + 3];
        float v0 = h[(size_t)s0 * DD + lane];
        float v1 = h[(size_t)s1 * DD + lane];
        float v2 = h[(size_t)s2 * DD + lane];
        float v3 = h[(size_t)s3 * DD + lane];
        acc = fmaf(v0, n0, acc);
        acc = fmaf(v1, n1, acc);
        acc = fmaf(v2, n2, acc);
        acc = fmaf(v3, n3, acc);
    }
    for (; e < e1; ++e) {
        int s = es[e];
        acc = fmaf(h[(size_t)s * DD + lane], enorm[e], acc);
    }
    outp[rowoff] = acc;
}

extern "C" void kernel_launch(void* const* d_in, const int* in_sizes, int n_in,
                              void* d_out, int out_size, void* d_ws, size_t ws_size,
                              hipStream_t stream) {
    const float* x  = (const float*)d_in[0];
    const int*   ei = (const int*)d_in[1];
    const float* W1 = (const float*)d_in[2];
    const float* b1 = (const float*)d_in[3];
    const float* W2 = (const float*)d_in[4];
    const float* b2 = (const float*)d_in[5];
    const float* p1 = (const float*)d_in[6];
    const float* p2 = (const float*)d_in[7];
    float* out = (float*)d_out;

    int n = in_sizes[0] / FIN;
    int E = in_sizes[1] / 2;
    const int* src = ei;
    const int* dst = ei + E;

    char* ws = (char*)d_ws;
    size_t off = 0;
    int* deg    = (int*)(ws + off); off += sizeof(int) * (size_t)n;
    int* rowptr = (int*)(ws + off); off += sizeof(int) * (size_t)(n + 1);
    int* cursor = (int*)(ws + off); off += sizeof(int) * (size_t)n;
    float* rs   = (float*)(ws + off); off += sizeof(float) * (size_t)n;
    int* es     = (int*)(ws + off); off += sizeof(int) * (size_t)E;
    float* enorm= (float*)(ws + off); off += sizeof(float) * (size_t)E;
    float* h1   = (float*)(ws + off); off += sizeof(float) * (size_t)n * DD;  // reused as h2
    float* agg1 = (float*)(ws + off); off += sizeof(float) * (size_t)n * DD;

    int nb = (n + 255) / 256;
    int eb = (E + 255) / 256;
    int ab = (n + 3) / 4;  // one wave per node, 4 waves/block

    k_deg_init<<<nb, 256, 0, stream>>>(deg, n);
    k_deg_count<<<eb, 256, 0, stream>>>(dst, deg, E);
    k_rs<<<nb, 256, 0, stream>>>(deg, rs, n);
    k_scan<<<1, 1024, 0, stream>>>(deg, rowptr, n);
    hipMemsetAsync(cursor, 0, sizeof(int) * (size_t)n, stream);
    k_place<<<eb, 256, 0, stream>>>(src, dst, rs, rowptr, cursor, es, enorm, E);

    k_gemm1<<<2048, 256, 0, stream>>>(x, W1, h1, n);
    k_agg<<<ab, 256, 0, stream>>>(h1, es, enorm, rowptr, rs, b1, p1, agg1, n);

    k_gemm2<<<2048, 256, 0, stream>>>(agg1, W2, h1, n);  // h1 reused as h2
    k_agg<<<ab, 256, 0, stream>>>(h1, es, enorm, rowptr, rs, b2, p2, out, n);
}

// Round 3
// 470.569 us; speedup vs baseline: 1.9322x; 1.1699x over previous
//
#include <hip/hip_runtime.h>

#define DD 64
#define FIN 128

__global__ __launch_bounds__(256) void k_deg_count(const int* __restrict__ dst,
                                                   int* __restrict__ deg, int E) {
    int e = blockIdx.x * 256 + threadIdx.x;
    if (e < E) atomicAdd(&deg[dst[e]], 1);
}

// per-block sums of deg (raw edge counts)
__global__ __launch_bounds__(256) void k_scanA(const int* __restrict__ deg,
                                               int* __restrict__ partial, int n) {
    __shared__ int wsum[4];
    int i = blockIdx.x * 256 + threadIdx.x;
    int v = (i < n) ? deg[i] : 0;
    for (int off = 32; off; off >>= 1) v += __shfl_down(v, off, 64);
    int lane = threadIdx.x & 63, wid = threadIdx.x >> 6;
    if (lane == 0) wsum[wid] = v;
    __syncthreads();
    if (threadIdx.x == 0) partial[blockIdx.x] = wsum[0] + wsum[1] + wsum[2] + wsum[3];
}

// exclusive scan of partials (nb <= 512), writes grand total to *total
__global__ __launch_bounds__(512) void k_scanB(int* __restrict__ partial, int nb,
                                               int* __restrict__ total) {
    __shared__ int wsum[8];
    int v = (threadIdx.x < (unsigned)nb) ? partial[threadIdx.x] : 0;
    int lane = threadIdx.x & 63, wid = threadIdx.x >> 6;
    int s = v;
    for (int off = 1; off < 64; off <<= 1) {
        int t = __shfl_up(s, off, 64);
        if (lane >= off) s += t;
    }
    if (lane == 63) wsum[wid] = s;
    __syncthreads();
    int wo = 0;
    for (int w = 0; w < wid; ++w) wo += wsum[w];
    int excl = s - v + wo;
    if (threadIdx.x < (unsigned)nb) partial[threadIdx.x] = excl;
    if (threadIdx.x == (unsigned)(nb - 1)) *total = excl + v;
}

// per-block exclusive scan + block offset -> rowptr; also cursor=rowptr, rs=rsqrt(deg+1)
__global__ __launch_bounds__(256) void k_scanC(const int* __restrict__ deg,
                                               const int* __restrict__ partial,
                                               int* __restrict__ rowptr,
                                               int* __restrict__ cursor,
                                               float* __restrict__ rs, int n) {
    __shared__ int wsum[4];
    int i = blockIdx.x * 256 + threadIdx.x;
    int v = (i < n) ? deg[i] : 0;
    int lane = threadIdx.x & 63, wid = threadIdx.x >> 6;
    int s = v;
    for (int off = 1; off < 64; off <<= 1) {
        int t = __shfl_up(s, off, 64);
        if (lane >= off) s += t;
    }
    if (lane == 63) wsum[wid] = s;
    __syncthreads();
    int wo = partial[blockIdx.x];
    for (int w = 0; w < wid; ++w) wo += wsum[w];
    int excl = s - v + wo;
    if (i < n) {
        rowptr[i] = excl;
        cursor[i] = excl;
        rs[i] = rsqrtf((float)(v + 1));
    }
}

__global__ __launch_bounds__(256) void k_place(const int* __restrict__ src,
                                               const int* __restrict__ dst,
                                               int* __restrict__ cursor,
                                               int* __restrict__ es, int E) {
    int e = blockIdx.x * 256 + threadIdx.x;
    if (e < E) {
        int s = src[e], d = dst[e];
        int pos = atomicAdd(&cursor[d], 1);
        es[pos] = s;
    }
}

// out[row][col] = (x[row,:] @ W[:,col]) * rs[row]   -- W column in VGPRs, x via scalar loads
__global__ __launch_bounds__(256) void k_gemm1(const float* __restrict__ x,
                                               const float* __restrict__ W,
                                               const float* __restrict__ rs,
                                               float* __restrict__ out, int n) {
    int col = threadIdx.x & 63;
    int wid = threadIdx.x >> 6;
    float w[FIN];
#pragma unroll
    for (int k = 0; k < FIN; ++k) w[k] = W[k * DD + col];
    int wave = blockIdx.x * 4 + wid;
    int nw = gridDim.x * 4;
    for (int row = wave; row < n; row += nw) {
        int urow = __builtin_amdgcn_readfirstlane(row);
        const float* xr = x + (size_t)urow * FIN;
        float a0 = 0.f, a1 = 0.f, a2 = 0.f, a3 = 0.f;
#pragma unroll
        for (int k = 0; k < FIN; k += 4) {
            a0 = fmaf(xr[k],     w[k],     a0);
            a1 = fmaf(xr[k + 1], w[k + 1], a1);
            a2 = fmaf(xr[k + 2], w[k + 2], a2);
            a3 = fmaf(xr[k + 3], w[k + 3], a3);
        }
        out[(size_t)urow * DD + col] = (a0 + a1 + a2 + a3) * rs[urow];
    }
}

// out[row][col] = (relu(a[row,:]) @ W[:,col]) * rs[row]
__global__ __launch_bounds__(256) void k_gemm2(const float* __restrict__ a,
                                               const float* __restrict__ W,
                                               const float* __restrict__ rs,
                                               float* __restrict__ out, int n) {
    int col = threadIdx.x & 63;
    int wid = threadIdx.x >> 6;
    float w[DD];
#pragma unroll
    for (int k = 0; k < DD; ++k) w[k] = W[k * DD + col];
    int wave = blockIdx.x * 4 + wid;
    int nw = gridDim.x * 4;
    for (int row = wave; row < n; row += nw) {
        int urow = __builtin_amdgcn_readfirstlane(row);
        const float* ar = a + (size_t)urow * DD;
        float a0 = 0.f, a1 = 0.f, a2 = 0.f, a3 = 0.f;
#pragma unroll
        for (int k = 0; k < DD; k += 4) {
            a0 = fmaf(fmaxf(ar[k],     0.f), w[k],     a0);
            a1 = fmaf(fmaxf(ar[k + 1], 0.f), w[k + 1], a1);
            a2 = fmaf(fmaxf(ar[k + 2], 0.f), w[k + 2], a2);
            a3 = fmaf(fmaxf(ar[k + 3], 0.f), w[k + 3], a3);
        }
        out[(size_t)urow * DD + col] = (a0 + a1 + a2 + a3) * rs[urow];
    }
}

// out[d] = b + pert[d] + rs[d] * (hp[d] + sum_e hp[src_e]),  hp = h*rs
__global__ __launch_bounds__(256) void k_agg(const float* __restrict__ hp,
                                             const int* __restrict__ es,
                                             const int* __restrict__ rowptr,
                                             const float* __restrict__ rs,
                                             const float* __restrict__ b,
                                             const float* __restrict__ pert,
                                             float* __restrict__ outp, int n) {
    int lane = threadIdx.x & 63;
    int w = threadIdx.x >> 6;
    int node = blockIdx.x * 4 + w;
    if (node >= n) return;
    node = __builtin_amdgcn_readfirstlane(node);
    int e0 = rowptr[node], e1 = rowptr[node + 1];
    size_t rowoff = (size_t)node * DD + lane;
    float a0 = hp[rowoff], a1 = 0.f, a2 = 0.f, a3 = 0.f;  // self-loop term
    int e = e0;
    for (; e + 4 <= e1; e += 4) {
        int s0 = es[e], s1 = es[e + 1], s2 = es[e + 2], s3 = es[e + 3];
        a0 += hp[(size_t)s0 * DD + lane];
        a1 += hp[(size_t)s1 * DD + lane];
        a2 += hp[(size_t)s2 * DD + lane];
        a3 += hp[(size_t)s3 * DD + lane];
    }
    for (; e < e1; ++e) a0 += hp[(size_t)es[e] * DD + lane];
    outp[rowoff] = fmaf(rs[node], a0 + a1 + a2 + a3, b[lane] + pert[rowoff]);
}

extern "C" void kernel_launch(void* const* d_in, const int* in_sizes, int n_in,
                              void* d_out, int out_size, void* d_ws, size_t ws_size,
                              hipStream_t stream) {
    const float* x  = (const float*)d_in[0];
    const int*   ei = (const int*)d_in[1];
    const float* W1 = (const float*)d_in[2];
    const float* b1 = (const float*)d_in[3];
    const float* W2 = (const float*)d_in[4];
    const float* b2 = (const float*)d_in[5];
    const float* p1 = (const float*)d_in[6];
    const float* p2 = (const float*)d_in[7];
    float* out = (float*)d_out;

    int n = in_sizes[0] / FIN;
    int E = in_sizes[1] / 2;
    const int* src = ei;
    const int* dst = ei + E;

    char* ws = (char*)d_ws;
    size_t off = 0;
    int* deg     = (int*)(ws + off); off += sizeof(int) * (size_t)n;
    int* partial = (int*)(ws + off); off += sizeof(int) * 512;
    int* rowptr  = (int*)(ws + off); off += sizeof(int) * (size_t)(n + 1);
    int* cursor  = (int*)(ws + off); off += sizeof(int) * (size_t)n;
    float* rs    = (float*)(ws + off); off += sizeof(float) * (size_t)n;
    int* es      = (int*)(ws + off); off += sizeof(int) * (size_t)E;
    float* h1    = (float*)(ws + off); off += sizeof(float) * (size_t)n * DD;  // reused as h2
    float* agg1  = (float*)(ws + off); off += sizeof(float) * (size_t)n * DD;

    int nb = (n + 255) / 256;   // 391 <= 512 for n=100k
    int eb = (E + 255) / 256;
    int ab = (n + 3) / 4;

    hipMemsetAsync(deg, 0, sizeof(int) * (size_t)n, stream);
    k_deg_count<<<eb, 256, 0, stream>>>(dst, deg, E);
    k_scanA<<<nb, 256, 0, stream>>>(deg, partial, n);
    k_scanB<<<1, 512, 0, stream>>>(partial, nb, rowptr + n);
    k_scanC<<<nb, 256, 0, stream>>>(deg, partial, rowptr, cursor, rs, n);
    k_place<<<eb, 256, 0, stream>>>(src, dst, cursor, es, E);

    k_gemm1<<<1024, 256, 0, stream>>>(x, W1, rs, h1, n);
    k_agg<<<ab, 256, 0, stream>>>(h1, es, rowptr, rs, b1, p1, agg1, n);

    k_gemm2<<<1024, 256, 0, stream>>>(agg1, W2, rs, h1, n);
    k_agg<<<ab, 256, 0, stream>>>(h1, es, rowptr, rs, b2, p2, out, n);
}